// Round 13
// baseline (98.015 us; speedup 1.0000x reference)
//
#include <hip/hip_runtime.h>
#include <math.h>

// Problem constants
#define RDIM 512
#define MDIM 4
#define LDIM 256
#define BDIM 8192
#define NROWS (BDIM * (RDIM / MDIM))   // 1048576 rows of m=4
#define SIGMA_EPS 1e-4f
#define LOG2E 1.4426950408889634f
#define SHIFT_HEADROOM 96.0f           // exp2 recentre: args in (-inf, 96], cancels in q=e/den

typedef _Float16 half4_t __attribute__((ext_vector_type(4)));
typedef short    short8_t __attribute__((ext_vector_type(8)));
typedef __fp16   fp16x2_t __attribute__((ext_vector_type(2)));
typedef float    float4_t __attribute__((ext_vector_type(4)));

#define NRT (NROWS / 16)          // 65536 row-tiles of 16 z-rows
#define MAIN_BLOCKS 2048
#define WPB 4                      // waves per block
#define NT (NRT / (MAIN_BLOCKS * WPB))   // 8 row-tiles per wave (walked in pairs)
#define QUAD 2                     // interleaved independent tile-chains per wave

static __device__ __host__ inline unsigned short bf16_rne(float f) {
  unsigned u = __builtin_bit_cast(unsigned, f);
  return (unsigned short)((u + 0x7FFFu + ((u >> 16) & 1u)) >> 16);
}

// ---------------- prep: build MFMA A-operand fragments in ws ----------------
// GEMM1 (scores, 16x16x16 f16): A1[m=center][k], 16 tiles of 16 centers.
//   k by quad: q0,q1 -> uh0..3, q2 -> ul0..3, q3 -> [bh, bl, 1, 1]
//   (u = 2*sig*log2e*c hi/lo f16 split, b = -sig*log2e*||c||^2 split).
//   B1 z-slots: q0 -> zh, q1 -> zl, q2 -> zh, q3 -> [1,1, -U_h,-U_l]
//   U = sig*log2e*||z||^2 - 96 (upper-bound shift, no max pass; 96 headroom
//   prevents den==0 underflow NaN — R9 lesson).
// GEMM2 (out^T = C2 @ Q, 16x16x32 bf16): 8 K-tiles, PERMUTED center order
//   center(p, k=8Q+j) = 32p + 16*(j>>2) + 4Q + (j&3)
//   rows m=0..3: bf16_rne(c); m=4: 1.0 (den row).
// B2 q-fragments are lane-local GEMM1 D registers (no LDS transform).
// A2 is staged to LDS by the main kernel (block-uniform) to free 32 VGPRs.
__global__ void prep_kernel(const float* __restrict__ c, const float* __restrict__ sigma,
                            _Float16* __restrict__ a1w, unsigned short* __restrict__ a2w) {
  const int gid  = blockIdx.x * 256 + threadIdx.x;
  const int lane = gid & 63;
  const int q4   = lane >> 4;
  const int m    = lane & 15;
  const float sig   = fmaxf(sigma[0], 0.0f) + SIGMA_EPS;
  const float sigL  = sig * LOG2E;
  const float sig2L = 2.0f * sigL;
  if (gid < 1024) {
    const int t = gid >> 6;        // A1 tile
    const int l = t * 16 + m;      // center
    float cv[4];
    cv[0] = c[l]; cv[1] = c[256 + l]; cv[2] = c[512 + l]; cv[3] = c[768 + l];
    _Float16 uh[4], ul[4];
    #pragma unroll
    for (int i = 0; i < 4; ++i) {
      float u = sig2L * cv[i];
      uh[i] = (_Float16)u;
      ul[i] = (_Float16)(u - (float)uh[i]);
    }
    float bias = -sigL * fmaf(cv[0], cv[0], fmaf(cv[1], cv[1], fmaf(cv[2], cv[2], cv[3] * cv[3])));
    _Float16 bh = (_Float16)bias;
    _Float16 bl = (_Float16)(bias - (float)bh);
    #pragma unroll
    for (int j = 0; j < 4; ++j) {
      _Float16 v;
      if      (q4 <  2) v = uh[j];
      else if (q4 == 2) v = ul[j];
      else              v = (j == 0) ? bh : ((j == 1) ? bl : (_Float16)1.0f);  // k14/15 pair -U
      a1w[(t * 64 + lane) * 4 + j] = v;
    }
  } else if (gid < 1536) {
    const int p = (gid - 1024) >> 6;   // A2 K-tile, 0..7
    #pragma unroll
    for (int j = 0; j < 8; ++j) {
      int center = 32 * p + 16 * (j >> 2) + 4 * q4 + (j & 3);   // permuted order
      unsigned short v = 0;
      if (m < 4)       v = bf16_rne(c[m * 256 + center]);
      else if (m == 4) v = (unsigned short)0x3F80;              // den ones-row
      a2w[(p * 64 + lane) * 8 + j] = v;
    }
  }
}

union U2H4 { uint2 u; half4_t h; };
union U4S8 { uint4 u; short8_t s; };

static __device__ __forceinline__ U2H4 make_b1(const float4& z, float sigL, int q4,
                                               unsigned one_one) {
  fp16x2_t zh01 = __builtin_amdgcn_cvt_pkrtz(z.x, z.y);
  fp16x2_t zh23 = __builtin_amdgcn_cvt_pkrtz(z.z, z.w);
  fp16x2_t zl01 = __builtin_amdgcn_cvt_pkrtz(z.x - (float)zh01[0], z.y - (float)zh01[1]);
  fp16x2_t zl23 = __builtin_amdgcn_cvt_pkrtz(z.z - (float)zh23[0], z.w - (float)zh23[1]);
  const unsigned zh01u = __builtin_bit_cast(unsigned, zh01);
  const unsigned zh23u = __builtin_bit_cast(unsigned, zh23);
  const unsigned zl01u = __builtin_bit_cast(unsigned, zl01);
  const unsigned zl23u = __builtin_bit_cast(unsigned, zl23);
  float U = sigL * fmaf(z.x, z.x, fmaf(z.y, z.y, fmaf(z.z, z.z, z.w * z.w))) - SHIFT_HEADROOM;
  float Uh = (float)(_Float16)U;
  fp16x2_t nU = __builtin_amdgcn_cvt_pkrtz(-Uh, -(U - Uh));
  const unsigned w0 = (q4 == 1) ? zl01u : ((q4 == 3) ? one_one : zh01u);
  const unsigned w1 = (q4 == 3) ? __builtin_bit_cast(unsigned, nU)
                                : ((q4 == 1) ? zl23u : zh23u);
  U2H4 b1; b1.u = make_uint2(w0, w1);
  return b1;
}

// ---------------- main ----------------
// QUAD=2 chains; a2 fragments staged once to LDS (block-uniform, contiguous
// 16B/lane ds_read_b128 = conflict-free) to cut persistent VGPRs 64 -> 32,
// __launch_bounds__(256,4) -> ~4 waves/SIMD for latency hiding (R12 lesson:
// more intra-wave ILP saturated; occupancy is the lever now).
__global__ __launch_bounds__(256, 4) void sq_mfma_kernel(
    const float4* __restrict__ x4,
    const _Float16* __restrict__ a1w,
    const unsigned short* __restrict__ a2w,
    const float* __restrict__ sigma,
    float4* __restrict__ out4) {
  const int tid  = threadIdx.x;
  const int lane = tid & 63;
  const int q4   = lane >> 4;
  const int zr   = lane & 15;

  __shared__ __align__(16) short8_t a2s[8 * 64];   // 8 KiB, shared by all 4 waves

  // stage A2 to LDS (512 entries, 256 threads -> 2 each)
  {
    const short8_t* a2p = (const short8_t*)a2w;
    a2s[tid]       = a2p[tid];
    a2s[tid + 256] = a2p[tid + 256];
  }

  const float sigL = (fmaxf(sigma[0], 0.0f) + SIGMA_EPS) * LOG2E;

  // preload loop-invariant A1 fragments (32 VGPR)
  half4_t a1[16];
  const half4_t* a1p = (const half4_t*)a1w;
  #pragma unroll
  for (int t = 0; t < 16; ++t) a1[t] = a1p[t * 64 + lane];

  __syncthreads();

  const int gw = blockIdx.x * WPB + (tid >> 6);
  const int tilebase = gw * NT;
  const float4_t zero4 = {0.f, 0.f, 0.f, 0.f};
  const unsigned one_one = 0x3C003C00u;   // f16 {1.0, 1.0}

  // prime the z pipeline (pair 0)
  float4 zq[QUAD];
  #pragma unroll
  for (int ch = 0; ch < QUAD; ++ch) zq[ch] = x4[(tilebase + ch) * 16 + zr];

  for (int it = 0; it < NT; it += QUAD) {
    // prefetch next pair (clamped)
    const int itn = (it + QUAD < NT) ? (it + QUAD) : it;
    float4 zn[QUAD];
    #pragma unroll
    for (int ch = 0; ch < QUAD; ++ch) zn[ch] = x4[(tilebase + itn + ch) * 16 + zr];

    U2H4 b1[QUAD];
    #pragma unroll
    for (int ch = 0; ch < QUAD; ++ch) b1[ch] = make_b1(zq[ch], sigL, q4, one_one);

    float4_t d2[QUAD];
    #pragma unroll
    for (int ch = 0; ch < QUAD; ++ch) d2[ch] = zero4;

    #pragma unroll
    for (int p = 0; p < 8; ++p) {
      const short8_t a2f = a2s[p * 64 + lane];   // ds_read_b128, conflict-free
      float4_t sa[QUAD], sb[QUAD];
      #pragma unroll
      for (int ch = 0; ch < QUAD; ++ch) {
        sa[ch] = __builtin_amdgcn_mfma_f32_16x16x16f16(a1[2 * p],     b1[ch].h, zero4, 0, 0, 0);
        sb[ch] = __builtin_amdgcn_mfma_f32_16x16x16f16(a1[2 * p + 1], b1[ch].h, zero4, 0, 0, 0);
      }
      #pragma unroll
      for (int ch = 0; ch < QUAD; ++ch) {
        float e0 = __builtin_amdgcn_exp2f(sa[ch][0]);
        float e1 = __builtin_amdgcn_exp2f(sa[ch][1]);
        float e2 = __builtin_amdgcn_exp2f(sa[ch][2]);
        float e3 = __builtin_amdgcn_exp2f(sa[ch][3]);
        float e4 = __builtin_amdgcn_exp2f(sb[ch][0]);
        float e5 = __builtin_amdgcn_exp2f(sb[ch][1]);
        float e6 = __builtin_amdgcn_exp2f(sb[ch][2]);
        float e7 = __builtin_amdgcn_exp2f(sb[ch][3]);
        U4S8 b2;
        b2.u.x = __builtin_amdgcn_perm(__builtin_bit_cast(unsigned, e1),
                                       __builtin_bit_cast(unsigned, e0), 0x07060302u);
        b2.u.y = __builtin_amdgcn_perm(__builtin_bit_cast(unsigned, e3),
                                       __builtin_bit_cast(unsigned, e2), 0x07060302u);
        b2.u.z = __builtin_amdgcn_perm(__builtin_bit_cast(unsigned, e5),
                                       __builtin_bit_cast(unsigned, e4), 0x07060302u);
        b2.u.w = __builtin_amdgcn_perm(__builtin_bit_cast(unsigned, e7),
                                       __builtin_bit_cast(unsigned, e6), 0x07060302u);
        d2[ch] = __builtin_amdgcn_mfma_f32_16x16x32_bf16(a2f, b2.s, d2[ch], 0, 0, 0);
      }
    }

    // den at D2 row 4 = quad1 reg0; out comps at rows 0..3 = quad0 regs
    float den[QUAD];
    #pragma unroll
    for (int ch = 0; ch < QUAD; ++ch) den[ch] = __shfl(d2[ch][0], zr + 16);
    if (lane < 16) {
      #pragma unroll
      for (int ch = 0; ch < QUAD; ++ch) {
        float r = __builtin_amdgcn_rcpf(den[ch]);
        out4[(tilebase + it + ch) * 16 + zr] =
            make_float4(d2[ch][0] * r, d2[ch][1] * r, d2[ch][2] * r, d2[ch][3] * r);
      }
    }

    #pragma unroll
    for (int ch = 0; ch < QUAD; ++ch) zq[ch] = zn[ch];
  }
}

extern "C" void kernel_launch(void* const* d_in, const int* in_sizes, int n_in,
                              void* d_out, int out_size, void* d_ws, size_t ws_size,
                              hipStream_t stream) {
  const float4* x4    = (const float4*)d_in[0];  // (B, R) fp32 = NROWS float4
  const float*  c     = (const float*)d_in[1];   // (M, L) fp32
  const float*  sigma = (const float*)d_in[2];   // (1,)  fp32
  float4*       out4  = (float4*)d_out;          // (B, R) fp32

  _Float16*       a1w = (_Float16*)d_ws;                 // 16*64*4 f16 = 8 KiB
  unsigned short* a2w = (unsigned short*)(a1w + 16 * 64 * 4);  // 8*64*8 bf16 = 8 KiB

  prep_kernel<<<6, 256, 0, stream>>>(c, sigma, a1w, a2w);
  sq_mfma_kernel<<<MAIN_BLOCKS, 256, 0, stream>>>(x4, a1w, a2w, sigma, out4);
}